// Round 11
// baseline (178.705 us; speedup 1.0000x reference)
//
#include <hip/hip_runtime.h>
#include <hip/hip_bf16.h>
#include <math.h>

#define BATCH 4
#define SEQ   4096
#define EMB   1024
#define HD    64
#define SCALE 0.03125f   // EMB^-0.5 = 1/32, exact in bf16

typedef __attribute__((ext_vector_type(8))) short short8;  // 8 bf16 = 4 VGPRs
typedef __attribute__((ext_vector_type(4))) float f32x4;

__device__ __forceinline__ short8 ld8g(const __hip_bfloat16* p) {
    union { uint4 u; short8 s; } cv;
    cv.u = *(const uint4*)p;
    return cv.s;
}
__device__ __forceinline__ short8 ld8l(const void* p) {
    union { uint4 u; short8 s; } cv;
    cv.u = *(const uint4*)p;
    return cv.s;
}
__device__ __forceinline__ unsigned short bfb(float a) {
    union { __hip_bfloat16 h; unsigned short u; } cv;
    cv.h = __hip_bfloat16(a);
    return cv.u;
}

// async global->LDS DMA, 16 B/lane. LDS dest = wave-uniform base + lane*16.
__device__ __forceinline__ void gld16(const void* g, const void* lds_base) {
    __builtin_amdgcn_global_load_lds(
        (const __attribute__((address_space(1))) void*)(unsigned long long)(uintptr_t)g,
        (__attribute__((address_space(3))) void*)(unsigned)(uintptr_t)lds_base,
        16, 0, 0);
}

// ---------------------------------------------------------------------------
// prep_w v2 (measured ~2-3 us, R8): coalesced transpose via padded LDS.
// ---------------------------------------------------------------------------
__global__ __launch_bounds__(256) void prep_w(
    const float* __restrict__ Wk, const float* __restrict__ Wq,
    const float* __restrict__ Wv, __hip_bfloat16* __restrict__ WT)
{
    __shared__ float ls[64][65];
    const int wsel = blockIdx.x >> 4;
    const int kblk = blockIdx.x & 15;
    const int k0   = kblk * 64;
    const float* W = (wsel == 0) ? Wq : (wsel == 1) ? Wk : Wv;
    const int t = threadIdx.x;
#pragma unroll
    for (int i = 0; i < 4; ++i) {
        const int idx = t + i * 256;
        const int row = idx >> 4;
        const int c4  = idx & 15;
        const float4 v = *(const float4*)(W + (size_t)(k0 + row) * HD + c4 * 4);
        ls[row][c4 * 4 + 0] = v.x; ls[row][c4 * 4 + 1] = v.y;
        ls[row][c4 * 4 + 2] = v.z; ls[row][c4 * 4 + 3] = v.w;
    }
    __syncthreads();
    const int h   = t >> 2;
    const int kk0 = (t & 3) * 16;
#pragma unroll
    for (int i = 0; i < 2; ++i) {
        const int kk = kk0 + i * 8;
        union { unsigned short u[8]; uint4 q; } pk;
#pragma unroll
        for (int j = 0; j < 8; ++j) pk.u[j] = bfb(ls[kk + j][h]);
        *(uint4*)(WT + (size_t)(wsel * 64 + h) * EMB + k0 + kk) = pk.q;
    }
}

// ---------------------------------------------------------------------------
// gemm_proj v4 VERBATIM from R7 (ledger-measured ~35 us): async DMA staging,
// global-side XOR swizzle, 512 blocks x 256 thr, block = 32 rows x 192 cols,
// single-buffered 2-barrier K-loop. R10's N-split (v6) regressed: x double-
// fetch (FETCH 34->66 MB) + 28x bank conflicts. Do not re-split N.
// ---------------------------------------------------------------------------
__global__ __launch_bounds__(256) void gemm_proj(
    const float* __restrict__ x,
    const __hip_bfloat16* __restrict__ WT,
    __hip_bfloat16* __restrict__ qs,
    __hip_bfloat16* __restrict__ kb,
    __hip_bfloat16* __restrict__ vT)
{
    __shared__ __align__(16) char sm[8 * 1040 + 24 * 1040];   // 33,280 B
    char* smA = sm;                    // A: 8 groups x 1040
    char* smB = sm + 8 * 1040;         // B: 24 groups x 1040

    const int tid  = threadIdx.x;
    const int lane = tid & 63;
    const int c    = lane & 15;
    const int quad = lane >> 4;
    const int w    = tid >> 6;
    const int rw   = w & 1;
    const int nh   = w >> 1;
    const int R0   = blockIdx.x * 32;

    const int rrA = lane >> 4;
    const int ciA = (lane & 15) ^ (rrA << 1);
    const int rrB = lane >> 3;
    const int ciB = (lane & 7) ^ rrB;

    const int rA  = rw * 16 + c;
    const int gA  = rA >> 2;
    const int rrr = rA & 3;
    const char* paBase = smA + gA * 1040 + rrr * 256;

    f32x4 acc[6];
#pragma unroll
    for (int f = 0; f < 6; ++f) acc[f] = (f32x4){0.f, 0.f, 0.f, 0.f};

    for (int s = 0; s < 16; ++s) {
        const int k0 = s * 64;

#pragma unroll
        for (int j = 0; j < 2; ++j) {
            const int g = w * 2 + j;
            const float* ga = x + (size_t)(R0 + g * 4 + rrA) * EMB + k0 + ciA * 4;
            gld16(ga, smA + g * 1040);
        }
#pragma unroll
        for (int j = 0; j < 6; ++j) {
            const int gb = w * 6 + j;
            const __hip_bfloat16* gw = WT + (size_t)(gb * 8 + rrB) * EMB + k0 + ciB * 8;
            gld16(gw, smB + gb * 1040);
        }
        __syncthreads();

#pragma unroll
        for (int ks = 0; ks < 2; ++ks) {
            const int ci0 = ks * 8 + quad * 2;
            const int ps0 = ci0 ^ (rrr << 1);
            const char* pa = paBase + ps0 * 16;
            const float4 fa = *(const float4*)pa;
            const float4 fb = *(const float4*)(pa + 16);
            union { unsigned short u[8]; short8 s8; } av;
            av.u[0] = bfb(fa.x); av.u[1] = bfb(fa.y);
            av.u[2] = bfb(fa.z); av.u[3] = bfb(fa.w);
            av.u[4] = bfb(fb.x); av.u[5] = bfb(fb.y);
            av.u[6] = bfb(fb.z); av.u[7] = bfb(fb.w);
#pragma unroll
            for (int f = 0; f < 6; ++f) {
                const int n   = nh * 96 + f * 16 + c;
                const int gB  = n >> 3;
                const int rB  = n & 7;
                const int psb = (ks * 4 + quad) ^ rB;
                const short8 bfrag = ld8l(smB + gB * 1040 + rB * 128 + psb * 16);
                acc[f] = __builtin_amdgcn_mfma_f32_16x16x32_bf16(av.s8, bfrag, acc[f], 0, 0, 0);
            }
        }
        __syncthreads();
    }

#pragma unroll
    for (int f = 0; f < 6; ++f) {
#pragma unroll
        for (int r = 0; r < 4; ++r) {
            const int m = R0 + rw * 16 + quad * 4 + r;
            const int n = nh * 96 + f * 16 + c;
            const float val = acc[f][r];
            if (n < 64) {
                qs[(size_t)m * HD + n] = __hip_bfloat16(val * SCALE);
            } else if (n < 128) {
                kb[(size_t)m * HD + (n - 64)] = __hip_bfloat16(val);
            } else {
                const int b  = m >> 12;
                const int sq = m & (SEQ - 1);
                const int sp = (sq & ~63) | ((sq & 15) << 2) | ((sq >> 4) & 3);
                vT[((size_t)b * HD + (n - 128)) * SEQ + sp] = __hip_bfloat16(val);
            }
        }
    }
}

// ---------------------------------------------------------------------------
// attn VERBATIM from R4/R6 (measured 66.2 us in R6) — the best-measured attn.
// Wave-autonomous: 4 waves per 16-row Q block, split-K by stripe, direct
// global K/V loads, Os/Ll LDS combine, direct out write. The R8-R10
// cooperative-DMA restructure (attn v3-v5) measured ~95-100 us — reverted.
// Co-resident blocks {g,g+256,g+512,g+768} get t={r,127-r,128+r,255-r}:
// per-CU visit sum ~131, balanced by construction.
// ---------------------------------------------------------------------------
__global__ __launch_bounds__(256, 4) void attn_kernel(
    const __hip_bfloat16* __restrict__ qs,
    const __hip_bfloat16* __restrict__ kb,
    const __hip_bfloat16* __restrict__ vT,
    float* __restrict__ out)
{
    __shared__ unsigned int Ps[4][16 * 36];   // per-wave P buffers (9216 B)
    __shared__ float Os[4][16][64];           // per-wave partial O (16 KB)
    __shared__ float Ll[4][16];               // per-wave partial l
    const int tid  = threadIdx.x;
    const int w    = tid >> 6;                // wave 0..3 = key-stripe
    const int lane = tid & 63;
    const int c    = lane & 15;
    const int quad = lane >> 4;

    const int g  = blockIdx.x;                // 0..1023
    const int b  = g & 3;
    const int jj = g >> 2;                    // 0..255
    const int m_ = jj >> 6, r_ = jj & 63;
    const int t  = (m_ == 0) ? r_ : (m_ == 1) ? (127 - r_)
                 : (m_ == 2) ? (128 + r_) : (255 - r_);
    const int q0 = t << 4;
    const int Td = t >> 2;                    // diagonal 64-key tile index

    const __hip_bfloat16* kbb = kb + (size_t)b * SEQ * HD;
    const __hip_bfloat16* vTb = vT + (size_t)b * HD * SEQ;

    const __hip_bfloat16* qp = qs + ((size_t)b * SEQ + q0 + c) * HD + quad * 8;
    const short8 aq0 = ld8g(qp);
    const short8 aq1 = ld8g(qp + 32);

    f32x4 o0 = {0.f,0.f,0.f,0.f}, o1 = o0, o2 = o0, o3 = o0;
    f32x4 lp = {0.f,0.f,0.f,0.f};
    const f32x4 z = {0.f,0.f,0.f,0.f};

    for (int T = w; T <= Td; T += 4) {
        const int k0 = T << 6;

        const __hip_bfloat16* kp = kbb + (size_t)(k0 + c) * HD + quad * 8;
        f32x4 sf[4];
#pragma unroll
        for (int f = 0; f < 4; ++f) {
            const short8 bk0 = ld8g(kp + f * (16 * HD));
            const short8 bk1 = ld8g(kp + f * (16 * HD) + 32);
            sf[f] = __builtin_amdgcn_mfma_f32_16x16x32_bf16(aq0, bk0, z, 0, 0, 0);
            sf[f] = __builtin_amdgcn_mfma_f32_16x16x32_bf16(aq1, bk1, sf[f], 0, 0, 0);
        }

        if (T == Td) {                        // diagonal tile: causal mask
#pragma unroll
            for (int f = 0; f < 4; ++f) {
                const int key = k0 + f * 16 + c;
#pragma unroll
                for (int r = 0; r < 4; ++r)
                    if (key > q0 + quad * 4 + r) sf[f][r] = -1e30f;
            }
        }

        float p[4][4];
#pragma unroll
        for (int f = 0; f < 4; ++f)
#pragma unroll
            for (int r = 0; r < 4; ++r)
                p[f][r] = __expf(sf[f][r]);
#pragma unroll
        for (int r = 0; r < 4; ++r) {
            lp[r] += (p[0][r] + p[1][r]) + (p[2][r] + p[3][r]);
            uint2 dd;
            dd.x = (unsigned int)bfb(p[0][r]) | ((unsigned int)bfb(p[1][r]) << 16);
            dd.y = (unsigned int)bfb(p[2][r]) | ((unsigned int)bfb(p[3][r]) << 16);
            *(uint2*)&Ps[w][(quad * 4 + r) * 36 + c * 2] = dd;   // pos = c*4 + f
        }

        const short8 ap0 = ld8l(&Ps[w][c * 36 + quad * 4]);
        const short8 ap1 = ld8l(&Ps[w][c * 36 + 16 + quad * 4]);

        const __hip_bfloat16* vp = vTb + (size_t)c * SEQ + k0 + quad * 8;
        {
            const short8 bv0 = ld8g(vp);
            const short8 bv1 = ld8g(vp + 32);
            o0 = __builtin_amdgcn_mfma_f32_16x16x32_bf16(ap0, bv0, o0, 0, 0, 0);
            o0 = __builtin_amdgcn_mfma_f32_16x16x32_bf16(ap1, bv1, o0, 0, 0, 0);
        }
        {
            const short8 bv0 = ld8g(vp + 16 * SEQ);
            const short8 bv1 = ld8g(vp + 16 * SEQ + 32);
            o1 = __builtin_amdgcn_mfma_f32_16x16x32_bf16(ap0, bv0, o1, 0, 0, 0);
            o1 = __builtin_amdgcn_mfma_f32_16x16x32_bf16(ap1, bv1, o1, 0, 0, 0);
        }
        {
            const short8 bv0 = ld8g(vp + 32 * SEQ);
            const short8 bv1 = ld8g(vp + 32 * SEQ + 32);
            o2 = __builtin_amdgcn_mfma_f32_16x16x32_bf16(ap0, bv0, o2, 0, 0, 0);
            o2 = __builtin_amdgcn_mfma_f32_16x16x32_bf16(ap1, bv1, o2, 0, 0, 0);
        }
        {
            const short8 bv0 = ld8g(vp + 48 * SEQ);
            const short8 bv1 = ld8g(vp + 48 * SEQ + 32);
            o3 = __builtin_amdgcn_mfma_f32_16x16x32_bf16(ap0, bv0, o3, 0, 0, 0);
            o3 = __builtin_amdgcn_mfma_f32_16x16x32_bf16(ap1, bv1, o3, 0, 0, 0);
        }
    }

    // per-wave l reduction across the 16 cols
#pragma unroll
    for (int r = 0; r < 4; ++r) {
        float v = lp[r];
        v += __shfl_xor(v, 1, 64);
        v += __shfl_xor(v, 2, 64);
        v += __shfl_xor(v, 4, 64);
        v += __shfl_xor(v, 8, 64);
        lp[r] = v;
    }

    // stage partials: Os[w][row][col], Ll[w][row]
#pragma unroll
    for (int r = 0; r < 4; ++r) {
        const int row = quad * 4 + r;
        Os[w][row][ 0 + c] = o0[r];
        Os[w][row][16 + c] = o1[r];
        Os[w][row][32 + c] = o2[r];
        Os[w][row][48 + c] = o3[r];
        if (c == 0) Ll[w][row] = lp[r];
    }
    __syncthreads();

    // combine: 256 threads x 4 elements, out = (sum o) / (sum l)
    float* ob = out + ((size_t)b * SEQ + q0) * HD;
#pragma unroll
    for (int i = 0; i < 4; ++i) {
        const int idx = tid + 256 * i;        // 0..1023
        const int row = idx >> 6;
        const int col = idx & 63;
        const float num = (Os[0][row][col] + Os[1][row][col])
                        + (Os[2][row][col] + Os[3][row][col]);
        const float den = (Ll[0][row] + Ll[1][row])
                        + (Ll[2][row] + Ll[3][row]);
        ob[row * HD + col] = num / den;
    }
}

// ---------------------------------------------------------------------------
extern "C" void kernel_launch(void* const* d_in, const int* in_sizes, int n_in,
                              void* d_out, int out_size, void* d_ws, size_t ws_size,
                              hipStream_t stream)
{
    (void)in_sizes; (void)n_in; (void)out_size; (void)ws_size;
    const float* x  = (const float*)d_in[0];
    const float* Wk = (const float*)d_in[1];
    const float* Wq = (const float*)d_in[2];
    const float* Wv = (const float*)d_in[3];
    float* out = (float*)d_out;

    const size_t BSH = (size_t)BATCH * SEQ * HD;        // 1,048,576 elems
    __hip_bfloat16* qs = (__hip_bfloat16*)d_ws;         // 2 MB
    __hip_bfloat16* kb = qs + BSH;                      // 2 MB
    __hip_bfloat16* vT = kb + BSH;                      // 2 MB
    __hip_bfloat16* WT = vT + BSH;                      // 384 KB (6.4 MB ws)

    prep_w<<<48, 256, 0, stream>>>(Wk, Wq, Wv, WT);
    gemm_proj<<<BATCH * SEQ / 32, 256, 0, stream>>>(x, WT, qs, kb, vT);
    attn_kernel<<<BATCH * (SEQ / 16), 256, 0, stream>>>(qs, kb, vT, out);
}